// Round 4
// baseline (194.525 us; speedup 1.0000x reference)
//
#include <hip/hip_runtime.h>
#include <cstdint>

#define N 8192
#define BLK 256
#define NBLOCKS 4096   // block b handles rows b and (N-2-b); combined length == N

// Load the 4 contiguous floats q[0..3] with the widest naturally-aligned accesses
// allowed by the compile-time phase R = (address of q) mod 4 (in floats).
//   R==0: one dwordx4 (lane-contiguous across the wave -> perfectly coalesced)
//   R==2: two dwordx2
//   R odd: dword + dwordx2 + dword   (q+1 is 8B-aligned for both R==1 and R==3)
// Values and their use order are identical to scalar q[0..3] -> bit-exact result.
template <int R>
__device__ __forceinline__ void load_xquad(const float* __restrict__ q,
                                           float& x0, float& x1, float& x2, float& x3) {
    if (R == 0) {
        const float4 v = *reinterpret_cast<const float4*>(q);
        x0 = v.x; x1 = v.y; x2 = v.z; x3 = v.w;
    } else if (R == 2) {
        const float2 a = *reinterpret_cast<const float2*>(q);
        const float2 b = *reinterpret_cast<const float2*>(q + 2);
        x0 = a.x; x1 = a.y; x2 = b.x; x3 = b.y;
    } else {
        x0 = q[0];
        const float2 m = *reinterpret_cast<const float2*>(q + 1);
        x1 = m.x; x2 = m.y;
        x3 = q[3];
    }
}

// Vector body with jam-4 (4 coeff dwordx4 + 4 x-quads in flight), folding into s
// in the EXACT ascending-v order of the round-0 kernel (bit-identical summation).
template <int R>
__device__ __forceinline__ float row_body(const float4* __restrict__ cv,
                                          const float* __restrict__ xv,
                                          int V, float s) {
    const int t = threadIdx.x;
    int v = t;
    for (; v + 3 * BLK < V; v += 4 * BLK) {
        const float4 c0 = cv[v];
        const float4 c1 = cv[v +     BLK];
        const float4 c2q = cv[v + 2 * BLK];
        const float4 c3 = cv[v + 3 * BLK];
        float x00, x01, x02, x03, x10, x11, x12, x13;
        float x20, x21, x22, x23, x30, x31, x32, x33;
        load_xquad<R>(xv + ((v            ) << 2), x00, x01, x02, x03);
        load_xquad<R>(xv + ((v +     BLK  ) << 2), x10, x11, x12, x13);
        load_xquad<R>(xv + ((v + 2 * BLK  ) << 2), x20, x21, x22, x23);
        load_xquad<R>(xv + ((v + 3 * BLK  ) << 2), x30, x31, x32, x33);
        s += c0.x * x00 + c0.y * x01 + c0.z * x02 + c0.w * x03;
        s += c1.x * x10 + c1.y * x11 + c1.z * x12 + c1.w * x13;
        s += c2q.x * x20 + c2q.y * x21 + c2q.z * x22 + c2q.w * x23;
        s += c3.x * x30 + c3.y * x31 + c3.z * x32 + c3.w * x33;
    }
    for (; v < V; v += BLK) {
        const float4 c = cv[v];
        float x0, x1, x2, x3;
        load_xquad<R>(xv + (v << 2), x0, x1, x2, x3);
        s += c.x * x0 + c.y * x1 + c.z * x2 + c.w * x3;
    }
    return s;
}

// Per-thread partial of sum_{e in [0,L)} c2[O+e] * x[i+1+e], strided over the block.
// Coeff stream 16B-aligned via prolog; x quads loaded at their natural alignment
// (phase R uniform per row). Summation order identical to the round-0 kernel.
__device__ __forceinline__ float row_partial(const float* __restrict__ c2,
                                             const float* __restrict__ x,
                                             long long O, int L, int i) {
    const int t = threadIdx.x;
    const float* cp = c2 + O;
    const float* xp = x + i + 1;
    float s = 0.0f;

    int pro = (int)((4 - (O & 3)) & 3);   // scalar elems until coeff 16B alignment
    if (pro > L) pro = L;
    if (t < pro) s += cp[t] * xp[t];

    const int Rm = L - pro;
    const int V = Rm >> 2;      // # of float4's
    const int tail = Rm & 3;

    const float4* __restrict__ cv = (const float4*)(cp + pro);
    const float*  __restrict__ xv = xp + pro;
    const int R = (i + 1 + pro) & 3;      // x-body phase (x base is 16B-aligned)

    switch (R) {
        case 0:  s = row_body<0>(cv, xv, V, s); break;
        case 1:  s = row_body<1>(cv, xv, V, s); break;
        case 2:  s = row_body<2>(cv, xv, V, s); break;
        default: s = row_body<3>(cv, xv, V, s); break;
    }

    if (t < tail) {
        const int e = (V << 2) + t;
        s += cp[pro + e] * xv[e];
    }
    return s;
}

__global__ __launch_bounds__(BLK) void ham_main(const float* __restrict__ x,
                                                const float* __restrict__ coeffs,
                                                float* __restrict__ ws) {
    const int b = blockIdx.x;
    const int t = threadIdx.x;
    const float* __restrict__ c1 = coeffs;
    const float* __restrict__ c2 = coeffs + N;

    float acc = 0.0f;

    // Row i1 = b  (length N-1-b)
    {
        const int i1 = b;
        const long long O1 = (long long)i1 * (2LL * N - i1 - 1) / 2;
        const int L1 = N - 1 - i1;
        const float s1 = row_partial(c2, x, O1, L1, i1);
        acc += x[i1] * s1;
    }
    // Row i2 = N-2-b  (length b+1); middle row (b==4095) appears only once
    {
        const int i2 = N - 2 - b;
        if (i2 > b) {
            const long long O2 = (long long)i2 * (2LL * N - i2 - 1) / 2;
            const int L2 = N - 1 - i2;
            const float s2 = row_partial(c2, x, O2, L2, i2);
            acc += x[i2] * s2;
        }
    }

    // Degree-1 terms: first 32 blocks cover 8192 elements
    {
        const int g = b * BLK + t;
        if (g < N) acc += c1[g] * x[g];
    }

    // Block reduction: wave shuffle (64-wide) then LDS across 4 waves
    #pragma unroll
    for (int o = 32; o > 0; o >>= 1) acc += __shfl_down(acc, o, 64);
    __shared__ float smem[BLK / 64];
    const int wave = t >> 6;
    const int lane = t & 63;
    if (lane == 0) smem[wave] = acc;
    __syncthreads();
    if (t == 0) {
        float v = 0.0f;
        #pragma unroll
        for (int w = 0; w < BLK / 64; ++w) v += smem[w];
        ws[b] = v;   // unconditional write: d_ws is poisoned, never read-before-write
    }
}

__global__ __launch_bounds__(1024) void ham_reduce(const float* __restrict__ ws,
                                                   float* __restrict__ out) {
    const int t = threadIdx.x;
    float v = 0.0f;
    for (int idx = t; idx < NBLOCKS; idx += 1024) v += ws[idx];
    #pragma unroll
    for (int o = 32; o > 0; o >>= 1) v += __shfl_down(v, o, 64);
    __shared__ float smem[16];
    const int wave = t >> 6;
    const int lane = t & 63;
    if (lane == 0) smem[wave] = v;
    __syncthreads();
    if (t == 0) {
        float s = 0.0f;
        #pragma unroll
        for (int w = 0; w < 16; ++w) s += smem[w];
        out[0] = s;
    }
}

extern "C" void kernel_launch(void* const* d_in, const int* in_sizes, int n_in,
                              void* d_out, int out_size, void* d_ws, size_t ws_size,
                              hipStream_t stream) {
    const float* x      = (const float*)d_in[0];
    const float* coeffs = (const float*)d_in[1];
    float* out = (float*)d_out;
    float* ws  = (float*)d_ws;   // needs NBLOCKS*4 = 16 KB

    ham_main<<<NBLOCKS, BLK, 0, stream>>>(x, coeffs, ws);
    ham_reduce<<<1, 1024, 0, stream>>>(ws, out);
}